// Round 3
// baseline (206.816 us; speedup 1.0000x reference)
//
#include <hip/hip_runtime.h>
#include <math.h>

// Problem constants (fixed by setup_inputs)
constexpr int Bb = 128;   // batch
constexpr int Nn = 2048;  // input capsules
constexpr int Dd = 8;     // input capsule dim
constexpr int Jj = 32;    // output capsules
constexpr int Pp = 16;    // output capsule dim

// Routing-pass tiling (R4/R7-proven): 512-thread blocks, 8 waves, BT=2.
constexpr int BT = 2;
constexpr int WV = 8;
constexpr int BB = BT * WV;      // 16 batches per block
constexpr int BN = 32;           // n per block
constexpr int NBC = Bb / BB;     // 8
constexpr int NNC = Nn / BN;     // 64
constexpr int GRID = NBC * NNC;  // 512
constexpr int SZ = Bb * Jj * Pp; // 65536 floats
constexpr size_t W16_ELEMS = (size_t)Jj * Nn * Pp * Dd;  // 8.39M halfs = 16.8 MB

typedef _Float16 half2v __attribute__((ext_vector_type(2)));
typedef _Float16 half8  __attribute__((ext_vector_type(8)));
typedef float    floatx4 __attribute__((ext_vector_type(4)));

#if __has_builtin(__builtin_amdgcn_fdot2)
__device__ inline float fdot2(half2v a, half2v b, float c) {
    return __builtin_amdgcn_fdot2(a, b, c, false);
}
#else
__device__ inline float fdot2(half2v a, half2v b, float c) {
    return (float)a.x * (float)b.x + (float)a.y * (float)b.y + c;
}
#endif

__device__ inline half2v bch2(unsigned u) { return __builtin_bit_cast(half2v, u); }
__device__ inline half8  bch8(uint4 u)    { return __builtin_bit_cast(half8, u); }
__device__ inline unsigned pkh2(float lo, float hi) {
    half2v h; h.x = (_Float16)lo; h.y = (_Float16)hi;   // v_cvt_f16_f32 (RTN)
    return __builtin_bit_cast(unsigned, h);
}

// ============================================================================
// R3: standalone W fp32 -> fp16 convert (pure linear stream, 50 MB).
// Layout preserved: W16 uint4 index = (j*2048 + n)*16 + p  (8 i-halves each),
// exactly what route_k's W16F path and gemm0_v3 consume.
// ============================================================================
__global__ __launch_bounds__(256)
void w16cvt_k(const float* __restrict__ W, ushort* __restrict__ W16)
{
    const size_t g = (size_t)blockIdx.x * 256 + threadIdx.x;  // uint4 index
    const float4* Wg = reinterpret_cast<const float4*>(W);
    float4 a = Wg[2 * g], b = Wg[2 * g + 1];
    uint4 o;
    o.x = pkh2(a.x, a.y); o.y = pkh2(a.z, a.w);
    o.z = pkh2(b.x, b.y); o.w = pkh2(b.z, b.w);
    reinterpret_cast<uint4*>(W16)[g] = o;
}

// ============================================================================
// Pass 0 GEMM, v3 (R3). v2 (~46 us) was latency-serialized: barrier + vmcnt(0)
// drain every K-step (incl. in-loop W16 write-through), prefetch depth 1,
// 2 barrier-groups/CU -> ~full HBM latency exposed 8x. v3 removes all of it:
//  - A-fragments load DIRECTLY from global W16: frag addr
//    ((jpc*4+f)*2048 + n)*16 + ar is 1 KB contiguous per 64-lane load,
//    L1-shared across the block's 8 waves (4 KB live A slice / K-step).
//  - x staged ONCE to a 64 KB LDS tile (one barrier total), one ds_read_b128
//    per K-step per wave.
//  - K-loop = 32 A-loads + 8 B-reads + 32 MFMA, ZERO barriers, zero stores:
//    compiler software-pipelines with counted vmcnt.
// Grid 512 = jpc(8) x nc(64); block = all 128 b (8 waves x 16). W read once.
// Writes same Sp[nc][b][jp] partials as before (reduce_squash unchanged).
// ============================================================================
__global__ __launch_bounds__(512, 2)
void gemm0_v3(const float* __restrict__ x, const ushort* __restrict__ W16,
              float* __restrict__ S)
{
    __shared__ uint4 xl[32 * 128];     // 64 KB fp16 x tile [nn][b]

    const int tid  = threadIdx.x;
    const int wave = tid >> 6;
    const int lane = tid & 63;

    const int id  = blockIdx.x;
    const int xcd = id & 7;
    const int rem = id >> 3;
    const int jpc = rem & 7;           // 8 jp-chunks of 64 (= 4 j each)
    const int nch = rem >> 3;          // 0..7
    const int nc  = xcd + 8 * nch;     // 0..63 n-chunk (K-slice)
    const int jp0 = jpc * 64;
    const int n0  = nc * 32;

    // ---- stage full x tile once: thread (b = t>>2, q = t&3), 8 n-groups ----
    {
        const int xb = tid >> 2, xq = tid & 3;
        const float4* Xg = reinterpret_cast<const float4*>(x);
        #pragma unroll
        for (int r = 0; r < 8; ++r) {
            const int nn = r * 4 + xq;
            const size_t base = ((size_t)xb * 2048 + n0 + nn) * 2;
            float4 a = Xg[base], b = Xg[base + 1];
            uint4 o;
            o.x = pkh2(a.x, a.y); o.y = pkh2(a.z, a.w);
            o.z = pkh2(b.x, b.y); o.w = pkh2(b.z, b.w);
            xl[nn * 128 + xb] = o;
        }
    }
    __syncthreads();

    const int ar = lane & 15;     // A row (p within j-tile) / B col (b)
    const int kg = lane >> 4;     // k-group -> n within 4-n K-step

    const uint4* W16v = reinterpret_cast<const uint4*>(W16);
    // Per-f A base: j = jpc*4 + f, frag uint4 idx = (j*2048 + n)*16 + ar.
    const size_t abase = ((size_t)(jpc * 4) * 2048 + n0 + kg) * 16 + ar;

    floatx4 acc[4];
    #pragma unroll
    for (int f = 0; f < 4; ++f)
        #pragma unroll
        for (int q = 0; q < 4; ++q) acc[f][q] = 0.f;

    #pragma unroll
    for (int ks = 0; ks < 8; ++ks) {
        half8 bfrag = bch8(xl[(ks * 4 + kg) * 128 + wave * 16 + ar]);
        #pragma unroll
        for (int f = 0; f < 4; ++f) {
            half8 afrag = bch8(W16v[abase + (size_t)f * 2048 * 16 + (size_t)ks * 4 * 16]);
            acc[f] = __builtin_amdgcn_mfma_f32_16x16x32_f16(afrag, bfrag, acc[f], 0, 0, 0);
        }
    }

    // ---- write partial slice Sp[nc][b][jp]; C: col=b, row(jp) = f*16+kg*4+q ----
    float* outp = S + (size_t)nc * SZ;
    const int bcol = wave * 16 + ar;
    #pragma unroll
    for (int f = 0; f < 4; ++f) {
        const size_t off = (size_t)bcol * 512 + jp0 + f * 16 + kg * 4;
        *reinterpret_cast<float4*>(outp + off) =
            make_float4(acc[f][0], acc[f][1], acc[f][2], acc[f][3]);
    }
}

// ============================================================================
// Pass 0 GEMM, v2 — kept ONLY for the no-W16-workspace fallback path.
// ============================================================================
template<int WT>
__global__ __launch_bounds__(512, 2)
void gemm0_k2(const float* __restrict__ x, const float* __restrict__ W,
              ushort* __restrict__ W16, float* __restrict__ S)
{
    __shared__ uint4 wl[2][256];   // [ns(4)][jpr(64)] fp16 W slice, dbuf (8 KB)
    __shared__ uint4 xl[2][512];   // [ns(4)][b(128)]  fp16 x slice, dbuf (16 KB)

    const int tid  = threadIdx.x;
    const int wave = tid >> 6;
    const int lane = tid & 63;

    const int id  = blockIdx.x;
    const int xcd = id & 7;
    const int rem = id >> 3;
    const int jpc = rem & 7;
    const int nch = rem >> 3;
    const int nc  = xcd + 8 * nch;
    const int jp0 = jpc * 64;
    const int n0  = nc * 32;

    const int wns = (tid >> 6) & 3;
    const int wjpr = tid & 63;
    const int wjp = jp0 + wjpr, wj = wjp >> 4, wp = wjp & 15;
    const int xb = tid >> 2, xq = tid & 3;

    const float4* Wg = reinterpret_cast<const float4*>(W);
    const float4* Xg = reinterpret_cast<const float4*>(x);
    uint4* W16v = reinterpret_cast<uint4*>(W16);

    float4 wa, wb2, xa, xb2;
    auto load_t = [&](int ks) {
        const int n = n0 + ks * 4;
        if (tid < 256) {
            const size_t base = ((size_t)wj * 2048 + (n + wns)) * 32 + wp * 2;
            wa = Wg[base]; wb2 = Wg[base + 1];
        }
        const size_t xbase = ((size_t)xb * 2048 + n) * 2 + xq * 2;
        xa = Xg[xbase]; xb2 = Xg[xbase + 1];
    };
    auto store_t = [&](int buf, int ks) {
        if (tid < 256) {
            uint4 o;
            o.x = pkh2(wa.x, wa.y);   o.y = pkh2(wa.z, wa.w);
            o.z = pkh2(wb2.x, wb2.y); o.w = pkh2(wb2.z, wb2.w);
            wl[buf][tid] = o;
            if (WT)
                W16v[((size_t)wj * 2048 + (n0 + ks * 4 + wns)) * 16 + wp] = o;
        }
        uint4 o2;
        o2.x = pkh2(xa.x, xa.y);   o2.y = pkh2(xa.z, xa.w);
        o2.z = pkh2(xb2.x, xb2.y); o2.w = pkh2(xb2.z, xb2.w);
        xl[buf][xq * 128 + xb] = o2;
    };

    floatx4 acc[4];
    #pragma unroll
    for (int f = 0; f < 4; ++f)
        #pragma unroll
        for (int q = 0; q < 4; ++q) acc[f][q] = 0.f;

    load_t(0);
    store_t(0, 0);
    __syncthreads();

    const int kg = lane >> 4;
    const int ar = lane & 15;

    for (int ks = 0; ks < 8; ++ks) {
        if (ks < 7) load_t(ks + 1);
        const int buf = ks & 1;

        half8 bfrag = bch8(xl[buf][kg * 128 + wave * 16 + ar]);
        #pragma unroll
        for (int f = 0; f < 4; ++f) {
            half8 afrag = bch8(wl[buf][kg * 64 + f * 16 + ar]);
            acc[f] = __builtin_amdgcn_mfma_f32_16x16x32_f16(afrag, bfrag, acc[f], 0, 0, 0);
        }

        if (ks < 7) {
            store_t(buf ^ 1, ks + 1);
            __syncthreads();
        }
    }

    float* outp = S + (size_t)nc * SZ;
    const int bcol = wave * 16 + ar;
    #pragma unroll
    for (int f = 0; f < 4; ++f) {
        const size_t off = (size_t)bcol * 512 + jp0 + f * 16 + kg * 4;
        *reinterpret_cast<float4*>(outp + off) =
            make_float4(acc[f][0], acc[f][1], acc[f][2], acc[f][3]);
    }
}

// Routing pass (R7 math, verbatim). W16F stages W from pre-converted fp16
// (1 uint4 load, no cvt; slot->(j,p) inverse of the compute-side swizzle).
// Swizzled W layout: chunk (l = j*2+hp, pp) at slot pp*64 + ((l+pp)&63).
// Lessons: R5/R6 = no hoisted index arrays / no unroll pragmas / BT=2 only;
// R8 = cooperative launch unsupported by harness.
template<int LOGITS, int ATOMIC, int W16F>
__global__ __launch_bounds__(512, 4)
void route_k(const float* __restrict__ x, const float* __restrict__ W,
             const ushort* __restrict__ W16,
             const float* __restrict__ OS, float* __restrict__ S)
{
    __shared__ uint4 wbuf[2][512];   // 2 x 8 KB fp16 W double buffer
    __shared__ uint4 xs[BB * BN];    // 8 KB fp16 x tile: [b][n] -> 8 halves

    const int tid  = threadIdx.x;
    const int wave = tid >> 6;
    const int lane = tid & 63;

    const int id  = blockIdx.x;
    const int xcd = id & 7;
    const int bc  = (id >> 3) & 7;
    const int nch = id >> 6;               // 0..7
    const int nc  = xcd + 8 * nch;         // 0..63
    const int b0  = bc * BB;
    const int n0  = nc * BN;
    const int j   = lane >> 1;
    const int hp  = lane & 1;              // p-half

    // ---- stage x tile as fp16: thread t -> (b = t>>5, n = t&31) ----
    {
        const int b = tid >> 5, n = tid & 31;
        const float4* src = reinterpret_cast<const float4*>(
            x + ((size_t)(b0 + b) * Nn + n0 + n) * Dd);
        float4 a = src[0], c4 = src[1];
        uint4 o;
        o.x = pkh2(a.x, a.y);  o.y = pkh2(a.z, a.w);
        o.z = pkh2(c4.x, c4.y); o.w = pkh2(c4.z, c4.w);
        xs[b * BN + n] = o;
    }

    // ---- W staging ----
    const float4* Wg = reinterpret_cast<const float4*>(W);
    const int sj = tid >> 4;
    const int sp = tid & 15;
    const int sl = sj * 2 + (sp >> 3);
    const int spp = sp & 7;
    const int wslot = spp * 64 + ((sl + spp) & 63);
    // fp16 path: thread t stages slot t; invert slot->(j,p).
    const int ispp = tid >> 6;
    const int isl  = ((tid & 63) - ispp) & 63;
    const int isj  = isl >> 1;
    const int isp  = ((isl & 1) << 3) | ispp;
    const uint4* W16v = reinterpret_cast<const uint4*>(W16);
    const size_t wbase16 = (size_t)isj * 32768 + isp;   // uint4 units

    float4 sta, stb;
    uint4 st16;
    auto load_slice = [&](int n) {
        if (W16F) {
            st16 = W16v[wbase16 + (size_t)n * 16];
        } else {
            const size_t base = (size_t)n * 32 + sp * 2 + (size_t)sj * ((size_t)Nn * 32);
            sta = Wg[base];
            stb = Wg[base + 1];
        }
    };
    auto store_slice = [&](int buf) {
        if (W16F) {
            wbuf[buf][tid] = st16;
        } else {
            uint4 o;
            o.x = pkh2(sta.x, sta.y);  o.y = pkh2(sta.z, sta.w);
            o.z = pkh2(stb.x, stb.y);  o.w = pkh2(stb.z, stb.w);
            wbuf[buf][wslot] = o;
        }
    };

    // Output-sum fragment for logits
    float osum[BT][8];
    if (LOGITS) {
        #pragma unroll
        for (int bb = 0; bb < BT; ++bb) {
            const float4* op = reinterpret_cast<const float4*>(
                OS + ((size_t)(b0 + wave * BT + bb) * Jj + j) * Pp + hp * 8);
            float4 a = op[0], b4 = op[1];
            osum[bb][0] = a.x;  osum[bb][1] = a.y;  osum[bb][2] = a.z;  osum[bb][3] = a.w;
            osum[bb][4] = b4.x; osum[bb][5] = b4.y; osum[bb][6] = b4.z; osum[bb][7] = b4.w;
        }
    }

    float Sa[BT][8];
    #pragma unroll
    for (int bb = 0; bb < BT; ++bb)
        #pragma unroll
        for (int pp = 0; pp < 8; ++pp) Sa[bb][pp] = 0.f;

    load_slice(n0);
    store_slice(0);
    __syncthreads();

    const uint4* xw = xs + (size_t)(wave * BT) * BN;   // this wave's x rows

    for (int nn = 0; nn < BN; ++nn) {
        if (nn + 1 < BN) load_slice(n0 + nn + 1);  // prefetch next slice to regs
        const int buf = nn & 1;

        // x rows (LDS broadcast, one b128 per batch): 8 halves = 4 half2
        half2v x01[BT], x23[BT], x45[BT], x67[BT];
        #pragma unroll
        for (int bb = 0; bb < BT; ++bb) {
            uint4 xr = xw[(size_t)bb * BN + nn];
            x01[bb] = bch2(xr.x); x23[bb] = bch2(xr.y);
            x45[bb] = bch2(xr.z); x67[bb] = bch2(xr.w);
        }

        // u_hat via fdot2 (f16 inputs, fp32 accumulate)
        float uh[BT][8];
        #pragma unroll
        for (int pp = 0; pp < 8; ++pp) {
            uint4 wv = wbuf[buf][pp * 64 + ((lane + pp) & 63)];
            half2v w01 = bch2(wv.x), w23 = bch2(wv.y);
            half2v w45 = bch2(wv.z), w67 = bch2(wv.w);
            #pragma unroll
            for (int bb = 0; bb < BT; ++bb) {
                float acc = fdot2(w01, x01[bb], 0.f);
                acc = fdot2(w23, x23[bb], acc);
                acc = fdot2(w45, x45[bb], acc);
                acc = fdot2(w67, x67[bb], acc);
                uh[bb][pp] = acc;
            }
        }

        if (!LOGITS) {
            #pragma unroll
            for (int bb = 0; bb < BT; ++bb)
                #pragma unroll
                for (int pp = 0; pp < 8; ++pp) Sa[bb][pp] += uh[bb][pp];
        } else {
            #pragma unroll
            for (int bb = 0; bb < BT; ++bb) {
                float lg = 0.f;
                #pragma unroll
                for (int pp = 0; pp < 8; ++pp)
                    lg = fmaf(osum[bb][pp], uh[bb][pp], lg);
                lg += __shfl_xor(lg, 1, 64);   // merge p-halves: full 16-p dot
                // softmax over j (no max-subtract; |lg| small): butterfly
                float e = __expf(lg);
                float se = e;
                #pragma unroll
                for (int mk = 2; mk <= 32; mk <<= 1)
                    se += __shfl_xor(se, mk, 64);
                float c = e * __builtin_amdgcn_rcpf(se);
                #pragma unroll
                for (int pp = 0; pp < 8; ++pp)
                    Sa[bb][pp] = fmaf(c, uh[bb][pp], Sa[bb][pp]);
            }
        }

        if (nn + 1 < BN) {
            store_slice((nn + 1) & 1);
            __syncthreads();
        }
    }

    // ---- flush block-partial S ----
    #pragma unroll
    for (int bb = 0; bb < BT; ++bb) {
        const size_t off = ((size_t)(b0 + wave * BT + bb) * Jj + j) * Pp + hp * 8;
        if (ATOMIC) {
            float* spd = S + off;
            #pragma unroll
            for (int pp = 0; pp < 8; ++pp) atomicAdd(spd + pp, Sa[bb][pp]);
        } else {
            float4* dst = reinterpret_cast<float4*>(S + (size_t)nc * SZ + off);
            dst[0] = make_float4(Sa[bb][0], Sa[bb][1], Sa[bb][2], Sa[bb][3]);
            dst[1] = make_float4(Sa[bb][4], Sa[bb][5], Sa[bb][6], Sa[bb][7]);
        }
    }
}

// Reduce nparts partial S slices, then squash. mode 0: OS=v; 1: OS+=v; 2: out=v.
// R9: 256 blocks x 64 threads spreads the 16.8 MB read over all 256 CUs.
__global__ void reduce_squash_k(const float* __restrict__ Sp, int nparts,
                                float scale, float* __restrict__ OS,
                                float* __restrict__ out, int mode)
{
    const int t = blockIdx.x * 64 + threadIdx.x;   // 0..16383
    const float4* sp = reinterpret_cast<const float4*>(Sp);
    float4 a = make_float4(0.f, 0.f, 0.f, 0.f);
    #pragma unroll 8
    for (int s = 0; s < nparts; ++s) {
        float4 v = sp[(size_t)s * (SZ / 4) + t];
        a.x += v.x; a.y += v.y; a.z += v.z; a.w += v.w;
    }
    a.x *= scale; a.y *= scale; a.z *= scale; a.w *= scale;
    float s2 = a.x * a.x + a.y * a.y + a.z * a.z + a.w * a.w;
    s2 += __shfl_xor(s2, 1, 64);   // 16 p = 4 consecutive threads
    s2 += __shfl_xor(s2, 2, 64);
    const float g = s2 / ((1.f + s2) * sqrtf(s2 + 1e-7f));
    float4 v = make_float4(g * a.x, g * a.y, g * a.z, g * a.w);
    if (mode == 0) {
        reinterpret_cast<float4*>(OS)[t] = v;
    } else if (mode == 1) {
        float4 o = reinterpret_cast<float4*>(OS)[t];
        o.x += v.x; o.y += v.y; o.z += v.z; o.w += v.w;
        reinterpret_cast<float4*>(OS)[t] = o;
    } else {
        reinterpret_cast<float4*>(out)[t] = v;
    }
}

extern "C" void kernel_launch(void* const* d_in, const int* in_sizes, int n_in,
                              void* d_out, int out_size, void* d_ws, size_t ws_size,
                              hipStream_t stream)
{
    const float* x = (const float*)d_in[0];   // [128, 2048, 8]
    const float* W = (const float*)d_in[1];   // [32, 2048, 16, 8]
    float* out = (float*)d_out;               // [128, 32, 16]

    const size_t needSp = (size_t)(NNC + 1) * SZ * sizeof(float);   // 16.9 MB
    const bool part  = ws_size >= needSp;
    const bool w16ok = ws_size >= needSp + W16_ELEMS * sizeof(ushort); // +16.8 MB
    dim3 rg(GRID), rb(512);
    dim3 sg(SZ / 4 / 64), sb(64);             // 256 blocks x 64 threads

    if (part) {
        float* Sp = (float*)d_ws;                 // [64][65536] partials
        float* OS = Sp + (size_t)NNC * SZ;        // running output sum
        ushort* W16 = (ushort*)(OS + SZ);         // fp16 W (if w16ok)

        if (w16ok) {
            const int cvtg = (int)(W16_ELEMS / 8 / 256);   // 4096 blocks
            w16cvt_k<<<dim3(cvtg), dim3(256), 0, stream>>>(W, W16);
            gemm0_v3<<<dim3(512), rb, 0, stream>>>(x, W16, Sp);
            reduce_squash_k<<<sg, sb, 0, stream>>>(Sp, NNC, 1.f / Jj, OS, out, 0);

            route_k<1, 0, 1><<<rg, rb, 0, stream>>>(x, W, W16, OS, Sp);
            reduce_squash_k<<<sg, sb, 0, stream>>>(Sp, NNC, 1.f, OS, out, 1);

            route_k<1, 0, 1><<<rg, rb, 0, stream>>>(x, W, W16, OS, Sp);
            reduce_squash_k<<<sg, sb, 0, stream>>>(Sp, NNC, 1.f, OS, out, 2);
        } else {
            gemm0_k2<0><<<dim3(512), rb, 0, stream>>>(x, W, nullptr, Sp);
            reduce_squash_k<<<sg, sb, 0, stream>>>(Sp, NNC, 1.f / Jj, OS, out, 0);

            route_k<1, 0, 0><<<rg, rb, 0, stream>>>(x, W, nullptr, OS, Sp);
            reduce_squash_k<<<sg, sb, 0, stream>>>(Sp, NNC, 1.f, OS, out, 1);

            route_k<1, 0, 0><<<rg, rb, 0, stream>>>(x, W, nullptr, OS, Sp);
            reduce_squash_k<<<sg, sb, 0, stream>>>(Sp, NNC, 1.f, OS, out, 2);
        }
    } else {
        float* S  = (float*)d_ws;
        float* OS = S + SZ;
        const size_t Sbytes = (size_t)SZ * sizeof(float);

        hipMemsetAsync(S, 0, Sbytes, stream);
        route_k<0, 1, 0><<<rg, rb, 0, stream>>>(x, W, nullptr, nullptr, S);
        reduce_squash_k<<<sg, sb, 0, stream>>>(S, 1, 1.f / Jj, OS, out, 0);

        hipMemsetAsync(S, 0, Sbytes, stream);
        route_k<1, 1, 0><<<rg, rb, 0, stream>>>(x, W, nullptr, OS, S);
        reduce_squash_k<<<sg, sb, 0, stream>>>(S, 1, 1.f, OS, out, 1);

        hipMemsetAsync(S, 0, Sbytes, stream);
        route_k<1, 1, 0><<<rg, rb, 0, stream>>>(x, W, nullptr, OS, S);
        reduce_squash_k<<<sg, sb, 0, stream>>>(S, 1, 1.f, OS, out, 2);
    }
}

// Round 4
// 176.293 us; speedup vs baseline: 1.1731x; 1.1731x over previous
//
#include <hip/hip_runtime.h>
#include <math.h>

// Problem constants (fixed by setup_inputs)
constexpr int Bb = 128;   // batch
constexpr int Nn = 2048;  // input capsules
constexpr int Dd = 8;     // input capsule dim
constexpr int Jj = 32;    // output capsules
constexpr int Pp = 16;    // output capsule dim

// Routing-pass tiling (R4/R7-proven): 512-thread blocks, 8 waves, BT=2.
constexpr int BT = 2;
constexpr int WV = 8;
constexpr int BB = BT * WV;      // 16 batches per block
constexpr int BN = 32;           // n per block
constexpr int NBC = Bb / BB;     // 8
constexpr int NNC = Nn / BN;     // 64
constexpr int GRID = NBC * NNC;  // 512
constexpr int SZ = Bb * Jj * Pp; // 65536 floats
constexpr size_t W16_ELEMS = (size_t)Jj * Nn * Pp * Dd;  // 8.39M halfs = 16.8 MB

typedef _Float16 half2v __attribute__((ext_vector_type(2)));
typedef _Float16 half8  __attribute__((ext_vector_type(8)));
typedef float    floatx4 __attribute__((ext_vector_type(4)));

#if __has_builtin(__builtin_amdgcn_fdot2)
__device__ inline float fdot2(half2v a, half2v b, float c) {
    return __builtin_amdgcn_fdot2(a, b, c, false);
}
#else
__device__ inline float fdot2(half2v a, half2v b, float c) {
    return (float)a.x * (float)b.x + (float)a.y * (float)b.y + c;
}
#endif

__device__ inline half2v bch2(unsigned u) { return __builtin_bit_cast(half2v, u); }
__device__ inline half8  bch8(uint4 u)    { return __builtin_bit_cast(half8, u); }
__device__ inline unsigned pkh2(float lo, float hi) {
    half2v h; h.x = (_Float16)lo; h.y = (_Float16)hi;   // v_cvt_f16_f32 (RTN)
    return __builtin_bit_cast(unsigned, h);
}

// ============================================================================
// W fp32 -> fp16 convert (pure linear stream, 50 MB).
// W16 uint4 index = (j*2048 + n)*16 + p  (8 i-halves each).
// ============================================================================
__global__ __launch_bounds__(256)
void w16cvt_k(const float* __restrict__ W, ushort* __restrict__ W16)
{
    const size_t g = (size_t)blockIdx.x * 256 + threadIdx.x;  // uint4 index
    const float4* Wg = reinterpret_cast<const float4*>(W);
    float4 a = Wg[2 * g], b = Wg[2 * g + 1];
    uint4 o;
    o.x = pkh2(a.x, a.y); o.y = pkh2(a.z, a.w);
    o.z = pkh2(b.x, b.y); o.w = pkh2(b.z, b.w);
    reinterpret_cast<uint4*>(W16)[g] = o;
}

// ============================================================================
// Pass 0 GEMM (uniform c): full-K MFMA, A direct from global W16, x in LDS.
// Proven R3. Grid 512 = jpc(8) x nc(64); block = all 128 b (8 waves x 16).
// ============================================================================
__global__ __launch_bounds__(512, 2)
void gemm0_v3(const float* __restrict__ x, const ushort* __restrict__ W16,
              float* __restrict__ S)
{
    __shared__ uint4 xl[32 * 128];     // 64 KB fp16 x tile [nn][b]

    const int tid  = threadIdx.x;
    const int wave = tid >> 6;
    const int lane = tid & 63;

    const int id  = blockIdx.x;
    const int xcd = id & 7;
    const int rem = id >> 3;
    const int jpc = rem & 7;           // 8 jp-chunks of 64 (= 4 j each)
    const int nch = rem >> 3;          // 0..7
    const int nc  = xcd + 8 * nch;     // 0..63 n-chunk (K-slice)
    const int jp0 = jpc * 64;
    const int n0  = nc * 32;

    {
        const int xb = tid >> 2, xq = tid & 3;
        const float4* Xg = reinterpret_cast<const float4*>(x);
        #pragma unroll
        for (int r = 0; r < 8; ++r) {
            const int nn = r * 4 + xq;
            const size_t base = ((size_t)xb * 2048 + n0 + nn) * 2;
            float4 a = Xg[base], b = Xg[base + 1];
            uint4 o;
            o.x = pkh2(a.x, a.y); o.y = pkh2(a.z, a.w);
            o.z = pkh2(b.x, b.y); o.w = pkh2(b.z, b.w);
            xl[nn * 128 + xb] = o;
        }
    }
    __syncthreads();

    const int ar = lane & 15;     // A row (p within j-tile) / B col (b)
    const int kg = lane >> 4;     // k-group -> n within 4-n K-step

    const uint4* W16v = reinterpret_cast<const uint4*>(W16);
    const size_t abase = ((size_t)(jpc * 4) * 2048 + n0 + kg) * 16 + ar;

    floatx4 acc[4];
    #pragma unroll
    for (int f = 0; f < 4; ++f)
        #pragma unroll
        for (int q = 0; q < 4; ++q) acc[f][q] = 0.f;

    #pragma unroll
    for (int ks = 0; ks < 8; ++ks) {
        half8 bfrag = bch8(xl[(ks * 4 + kg) * 128 + wave * 16 + ar]);
        #pragma unroll
        for (int f = 0; f < 4; ++f) {
            half8 afrag = bch8(W16v[abase + (size_t)f * 2048 * 16 + (size_t)ks * 4 * 16]);
            acc[f] = __builtin_amdgcn_mfma_f32_16x16x32_f16(afrag, bfrag, acc[f], 0, 0, 0);
        }
    }

    float* outp = S + (size_t)nc * SZ;
    const int bcol = wave * 16 + ar;
    #pragma unroll
    for (int f = 0; f < 4; ++f) {
        const size_t off = (size_t)bcol * 512 + jp0 + f * 16 + kg * 4;
        *reinterpret_cast<float4*>(outp + off) =
            make_float4(acc[f][0], acc[f][1], acc[f][2], acc[f][3]);
    }
}

// ============================================================================
// R4: Routing pass via masked-K MFMA (route_m).
// Structure: grid/XCD swizzle identical to route_k (8 bc x 64 nc). Per block:
// b-tile = 16 (MFMA cols), ALL jp = 512 (wave w owns j = 4w..4w+3, 4 tiles),
// n-chunk = 32 processed in 8 groups of 4 n (one MFMA K = 4n x 8i).
// Per-n separation: for mfma_16x16x32_f16, lane (kg=lane>>4, ar=lane&15)'s
// 8 B-halves are exactly k-octet kg -> selecting n=s of the 4-n group means
// zeroing whole lanes: bs = (kg==s) ? bfull : 0. (A/B/C lane mappings are the
// gemm0_v3-verified ones: A row = ar = p, k-octet = kg = n; C col = ar = b,
// C row = kg*4+q = p.)
// Logits: lg[f][s] = sum_p osum*uh -> 4-fma lane partial + xor16/32 allreduce.
// Softmax over j crosses waves: per-wave partial ef_sum[s] -> LDS pl (1 write,
// 1 barrier, 8 reads), c = e * rcp(se) stays in registers.
// A-frags stream from global W16 (1 KB contiguous per load, L2-shared by the
// 8 bc-sharers on the same XCD); prefetched one group ahead.
// DS per wave per pass ~2.2k cyc vs route_k's ~6.5k; u_hat on the matrix pipe.
// ============================================================================
__global__ __launch_bounds__(512, 2)
void route_m(const float* __restrict__ x, const ushort* __restrict__ W16,
             const float* __restrict__ OS, float* __restrict__ S)
{
    __shared__ uint4 xl[16 * 32];      // 8 KB fp16 x tile, slot n*16 + ((b+n)&15)
    __shared__ float pl[2][512];       // 4 KB per-wave se partials, dbuf

    const int tid  = threadIdx.x;
    const int w    = tid >> 6;
    const int lane = tid & 63;
    const int ar   = lane & 15;        // b (col) / p (A-row)
    const int kg   = lane >> 4;        // k-octet -> n within group / p-subrow (C)

    const int id  = blockIdx.x;
    const int xcd = id & 7;
    const int bc  = (id >> 3) & 7;
    const int nch = id >> 6;
    const int nc  = xcd + 8 * nch;     // 0..63
    const int b0  = bc * 16;
    const int n0  = nc * 32;

    // ---- stage x tile fp16, bank-rotated: t -> (b = t>>5, n = t&31) ----
    {
        const int b = tid >> 5, n = tid & 31;
        const float4* src = reinterpret_cast<const float4*>(
            x + ((size_t)(b0 + b) * Nn + n0 + n) * Dd);
        float4 a = src[0], c4 = src[1];
        uint4 o;
        o.x = pkh2(a.x, a.y);  o.y = pkh2(a.z, a.w);
        o.z = pkh2(c4.x, c4.y); o.w = pkh2(c4.z, c4.w);
        xl[n * 16 + ((b + n) & 15)] = o;
    }

    // ---- osum fragment: o4[f] = OS[b0+ar][j=4w+f][p=4kg..4kg+3] ----
    float4 o4[4];
    {
        const float4* osv = reinterpret_cast<const float4*>(OS);
        #pragma unroll
        for (int f = 0; f < 4; ++f)
            o4[f] = osv[((size_t)(b0 + ar) * Jj + (w * 4 + f)) * 4 + kg];
    }

    float Sa[4][4];
    #pragma unroll
    for (int f = 0; f < 4; ++f)
        #pragma unroll
        for (int q = 0; q < 4; ++q) Sa[f][q] = 0.f;

    const uint4* W16v = reinterpret_cast<const uint4*>(W16);

    __syncthreads();   // xl ready

    // A frags for group 0: aw[f] = W16[j=4w+f][n = n0+kg][p=ar][i*]
    uint4 aw[4];
    #pragma unroll
    for (int f = 0; f < 4; ++f)
        aw[f] = W16v[((size_t)(w * 4 + f) * Nn + n0 + kg) * 16 + ar];

    const half8 hz = {};

    for (int g = 0; g < 8; ++g) {
        const int nl = g * 4;

        // B: full 4-n fragment (lane kg holds n = nl+kg), then masked selects
        half8 bfull = bch8(xl[(nl + kg) * 16 + ((ar + nl + kg) & 15)]);

        floatx4 res[4][4];   // res[f][s] = uh[b=b0+ar][j=4w+f][n=nl+s][p=4kg+q]
        #pragma unroll
        for (int s = 0; s < 4; ++s) {
            half8 bs = (kg == s) ? bfull : hz;
            #pragma unroll
            for (int f = 0; f < 4; ++f) {
                floatx4 z = {0.f, 0.f, 0.f, 0.f};
                res[f][s] = __builtin_amdgcn_mfma_f32_16x16x32_f16(bch8(aw[f]), bs, z, 0, 0, 0);
            }
        }

        // prefetch next group's A while MFMAs retire
        uint4 awn[4];
        if (g < 7) {
            #pragma unroll
            for (int f = 0; f < 4; ++f)
                awn[f] = W16v[((size_t)(w * 4 + f) * Nn + n0 + nl + 4 + kg) * 16 + ar];
        }

        // ---- logits + exp ----
        float e[4][4];
        float efs0 = 0.f, efs1 = 0.f, efs2 = 0.f, efs3 = 0.f;
        #pragma unroll
        for (int f = 0; f < 4; ++f) {
            #pragma unroll
            for (int s = 0; s < 4; ++s) {
                float lg = o4[f].x * res[f][s][0];
                lg = fmaf(o4[f].y, res[f][s][1], lg);
                lg = fmaf(o4[f].z, res[f][s][2], lg);
                lg = fmaf(o4[f].w, res[f][s][3], lg);
                lg += __shfl_xor(lg, 16, 64);   // reduce over kg (p-groups)
                lg += __shfl_xor(lg, 32, 64);
                float ee = __expf(lg);
                e[f][s] = ee;
                if (s == 0) efs0 += ee; else if (s == 1) efs1 += ee;
                else if (s == 2) efs2 += ee; else efs3 += ee;
            }
        }

        // ---- cross-wave se: lane (kg,ar) publishes its wave's partial for s=kg
        float t01 = (kg & 1) ? efs1 : efs0;
        float t23 = (kg & 1) ? efs3 : efs2;
        float myp = (kg & 2) ? t23 : t01;
        pl[g & 1][w * 64 + lane] = myp;
        __syncthreads();

        float se = 0.f;
        #pragma unroll
        for (int ww = 0; ww < 8; ++ww) se += pl[g & 1][ww * 64 + lane];
        float rse = __builtin_amdgcn_rcpf(se);   // rse for (b=ar, n = nl+kg)

        // allgather rse over kg: value for s sits at idx = s^kg in {rse,r1,r2,r3}
        float r1 = __shfl_xor(rse, 16, 64);
        float r2 = __shfl_xor(rse, 32, 64);
        float r3 = __shfl_xor(r1, 32, 64);
        float rs[4];
        #pragma unroll
        for (int s = 0; s < 4; ++s) {
            float a01 = ((s ^ kg) & 1) ? r1 : rse;
            float a23 = ((s ^ kg) & 1) ? r3 : r2;
            rs[s] = ((s ^ kg) & 2) ? a23 : a01;
        }

        // ---- Sa += c * uh ----
        #pragma unroll
        for (int f = 0; f < 4; ++f) {
            #pragma unroll
            for (int s = 0; s < 4; ++s) {
                float c = e[f][s] * rs[s];
                #pragma unroll
                for (int q = 0; q < 4; ++q)
                    Sa[f][q] = fmaf(c, res[f][s][q], Sa[f][q]);
            }
        }

        if (g < 7) {
            #pragma unroll
            for (int f = 0; f < 4; ++f) aw[f] = awn[f];
        }
    }

    // ---- flush block-partial S: Sp[nc][b=b0+ar][jp=(4w+f)*16+4kg+q] ----
    float* outp = S + (size_t)nc * SZ + (size_t)(b0 + ar) * 512;
    #pragma unroll
    for (int f = 0; f < 4; ++f) {
        *reinterpret_cast<float4*>(outp + (w * 4 + f) * 16 + kg * 4) =
            make_float4(Sa[f][0], Sa[f][1], Sa[f][2], Sa[f][3]);
    }
}

// ============================================================================
// Pass 0 GEMM v2 — kept ONLY for the no-W16-workspace fallback path.
// ============================================================================
template<int WT>
__global__ __launch_bounds__(512, 2)
void gemm0_k2(const float* __restrict__ x, const float* __restrict__ W,
              ushort* __restrict__ W16, float* __restrict__ S)
{
    __shared__ uint4 wl[2][256];
    __shared__ uint4 xl[2][512];

    const int tid  = threadIdx.x;
    const int wave = tid >> 6;
    const int lane = tid & 63;

    const int id  = blockIdx.x;
    const int xcd = id & 7;
    const int rem = id >> 3;
    const int jpc = rem & 7;
    const int nch = rem >> 3;
    const int nc  = xcd + 8 * nch;
    const int jp0 = jpc * 64;
    const int n0  = nc * 32;

    const int wns = (tid >> 6) & 3;
    const int wjpr = tid & 63;
    const int wjp = jp0 + wjpr, wj = wjp >> 4, wp = wjp & 15;
    const int xb = tid >> 2, xq = tid & 3;

    const float4* Wg = reinterpret_cast<const float4*>(W);
    const float4* Xg = reinterpret_cast<const float4*>(x);
    uint4* W16v = reinterpret_cast<uint4*>(W16);

    float4 wa, wb2, xa, xb2;
    auto load_t = [&](int ks) {
        const int n = n0 + ks * 4;
        if (tid < 256) {
            const size_t base = ((size_t)wj * 2048 + (n + wns)) * 32 + wp * 2;
            wa = Wg[base]; wb2 = Wg[base + 1];
        }
        const size_t xbase = ((size_t)xb * 2048 + n) * 2 + xq * 2;
        xa = Xg[xbase]; xb2 = Xg[xbase + 1];
    };
    auto store_t = [&](int buf, int ks) {
        if (tid < 256) {
            uint4 o;
            o.x = pkh2(wa.x, wa.y);   o.y = pkh2(wa.z, wa.w);
            o.z = pkh2(wb2.x, wb2.y); o.w = pkh2(wb2.z, wb2.w);
            wl[buf][tid] = o;
            if (WT)
                W16v[((size_t)wj * 2048 + (n0 + ks * 4 + wns)) * 16 + wp] = o;
        }
        uint4 o2;
        o2.x = pkh2(xa.x, xa.y);   o2.y = pkh2(xa.z, xa.w);
        o2.z = pkh2(xb2.x, xb2.y); o2.w = pkh2(xb2.z, xb2.w);
        xl[buf][xq * 128 + xb] = o2;
    };

    floatx4 acc[4];
    #pragma unroll
    for (int f = 0; f < 4; ++f)
        #pragma unroll
        for (int q = 0; q < 4; ++q) acc[f][q] = 0.f;

    load_t(0);
    store_t(0, 0);
    __syncthreads();

    const int kg = lane >> 4;
    const int ar = lane & 15;

    for (int ks = 0; ks < 8; ++ks) {
        if (ks < 7) load_t(ks + 1);
        const int buf = ks & 1;

        half8 bfrag = bch8(xl[buf][kg * 128 + wave * 16 + ar]);
        #pragma unroll
        for (int f = 0; f < 4; ++f) {
            half8 afrag = bch8(wl[buf][kg * 64 + f * 16 + ar]);
            acc[f] = __builtin_amdgcn_mfma_f32_16x16x32_f16(afrag, bfrag, acc[f], 0, 0, 0);
        }

        if (ks < 7) {
            store_t(buf ^ 1, ks + 1);
            __syncthreads();
        }
    }

    float* outp = S + (size_t)nc * SZ;
    const int bcol = wave * 16 + ar;
    #pragma unroll
    for (int f = 0; f < 4; ++f) {
        const size_t off = (size_t)bcol * 512 + jp0 + f * 16 + kg * 4;
        *reinterpret_cast<float4*>(outp + off) =
            make_float4(acc[f][0], acc[f][1], acc[f][2], acc[f][3]);
    }
}

// Routing pass (R7 math, fdot2) — kept for fallback paths only.
template<int LOGITS, int ATOMIC, int W16F>
__global__ __launch_bounds__(512, 4)
void route_k(const float* __restrict__ x, const float* __restrict__ W,
             const ushort* __restrict__ W16,
             const float* __restrict__ OS, float* __restrict__ S)
{
    __shared__ uint4 wbuf[2][512];
    __shared__ uint4 xs[BB * BN];

    const int tid  = threadIdx.x;
    const int wave = tid >> 6;
    const int lane = tid & 63;

    const int id  = blockIdx.x;
    const int xcd = id & 7;
    const int bc  = (id >> 3) & 7;
    const int nch = id >> 6;
    const int nc  = xcd + 8 * nch;
    const int b0  = bc * BB;
    const int n0  = nc * BN;
    const int j   = lane >> 1;
    const int hp  = lane & 1;

    {
        const int b = tid >> 5, n = tid & 31;
        const float4* src = reinterpret_cast<const float4*>(
            x + ((size_t)(b0 + b) * Nn + n0 + n) * Dd);
        float4 a = src[0], c4 = src[1];
        uint4 o;
        o.x = pkh2(a.x, a.y);  o.y = pkh2(a.z, a.w);
        o.z = pkh2(c4.x, c4.y); o.w = pkh2(c4.z, c4.w);
        xs[b * BN + n] = o;
    }

    const float4* Wg = reinterpret_cast<const float4*>(W);
    const int sj = tid >> 4;
    const int sp = tid & 15;
    const int sl = sj * 2 + (sp >> 3);
    const int spp = sp & 7;
    const int wslot = spp * 64 + ((sl + spp) & 63);
    const int ispp = tid >> 6;
    const int isl  = ((tid & 63) - ispp) & 63;
    const int isj  = isl >> 1;
    const int isp  = ((isl & 1) << 3) | ispp;
    const uint4* W16v = reinterpret_cast<const uint4*>(W16);
    const size_t wbase16 = (size_t)isj * 32768 + isp;

    float4 sta, stb;
    uint4 st16;
    auto load_slice = [&](int n) {
        if (W16F) {
            st16 = W16v[wbase16 + (size_t)n * 16];
        } else {
            const size_t base = (size_t)n * 32 + sp * 2 + (size_t)sj * ((size_t)Nn * 32);
            sta = Wg[base];
            stb = Wg[base + 1];
        }
    };
    auto store_slice = [&](int buf) {
        if (W16F) {
            wbuf[buf][tid] = st16;
        } else {
            uint4 o;
            o.x = pkh2(sta.x, sta.y);  o.y = pkh2(sta.z, sta.w);
            o.z = pkh2(stb.x, stb.y);  o.w = pkh2(stb.z, stb.w);
            wbuf[buf][wslot] = o;
        }
    };

    float osum[BT][8];
    if (LOGITS) {
        #pragma unroll
        for (int bb = 0; bb < BT; ++bb) {
            const float4* op = reinterpret_cast<const float4*>(
                OS + ((size_t)(b0 + wave * BT + bb) * Jj + j) * Pp + hp * 8);
            float4 a = op[0], b4 = op[1];
            osum[bb][0] = a.x;  osum[bb][1] = a.y;  osum[bb][2] = a.z;  osum[bb][3] = a.w;
            osum[bb][4] = b4.x; osum[bb][5] = b4.y; osum[bb][6] = b4.z; osum[bb][7] = b4.w;
        }
    }

    float Sa[BT][8];
    #pragma unroll
    for (int bb = 0; bb < BT; ++bb)
        #pragma unroll
        for (int pp = 0; pp < 8; ++pp) Sa[bb][pp] = 0.f;

    load_slice(n0);
    store_slice(0);
    __syncthreads();

    const uint4* xw = xs + (size_t)(wave * BT) * BN;

    for (int nn = 0; nn < BN; ++nn) {
        if (nn + 1 < BN) load_slice(n0 + nn + 1);
        const int buf = nn & 1;

        half2v x01[BT], x23[BT], x45[BT], x67[BT];
        #pragma unroll
        for (int bb = 0; bb < BT; ++bb) {
            uint4 xr = xw[(size_t)bb * BN + nn];
            x01[bb] = bch2(xr.x); x23[bb] = bch2(xr.y);
            x45[bb] = bch2(xr.z); x67[bb] = bch2(xr.w);
        }

        float uh[BT][8];
        #pragma unroll
        for (int pp = 0; pp < 8; ++pp) {
            uint4 wv = wbuf[buf][pp * 64 + ((lane + pp) & 63)];
            half2v w01 = bch2(wv.x), w23 = bch2(wv.y);
            half2v w45 = bch2(wv.z), w67 = bch2(wv.w);
            #pragma unroll
            for (int bb = 0; bb < BT; ++bb) {
                float acc = fdot2(w01, x01[bb], 0.f);
                acc = fdot2(w23, x23[bb], acc);
                acc = fdot2(w45, x45[bb], acc);
                acc = fdot2(w67, x67[bb], acc);
                uh[bb][pp] = acc;
            }
        }

        if (!LOGITS) {
            #pragma unroll
            for (int bb = 0; bb < BT; ++bb)
                #pragma unroll
                for (int pp = 0; pp < 8; ++pp) Sa[bb][pp] += uh[bb][pp];
        } else {
            #pragma unroll
            for (int bb = 0; bb < BT; ++bb) {
                float lg = 0.f;
                #pragma unroll
                for (int pp = 0; pp < 8; ++pp)
                    lg = fmaf(osum[bb][pp], uh[bb][pp], lg);
                lg += __shfl_xor(lg, 1, 64);
                float e = __expf(lg);
                float se = e;
                #pragma unroll
                for (int mk = 2; mk <= 32; mk <<= 1)
                    se += __shfl_xor(se, mk, 64);
                float c = e * __builtin_amdgcn_rcpf(se);
                #pragma unroll
                for (int pp = 0; pp < 8; ++pp)
                    Sa[bb][pp] = fmaf(c, uh[bb][pp], Sa[bb][pp]);
            }
        }

        if (nn + 1 < BN) {
            store_slice((nn + 1) & 1);
            __syncthreads();
        }
    }

    #pragma unroll
    for (int bb = 0; bb < BT; ++bb) {
        const size_t off = ((size_t)(b0 + wave * BT + bb) * Jj + j) * Pp + hp * 8;
        if (ATOMIC) {
            float* spd = S + off;
            #pragma unroll
            for (int pp = 0; pp < 8; ++pp) atomicAdd(spd + pp, Sa[bb][pp]);
        } else {
            float4* dst = reinterpret_cast<float4*>(S + (size_t)nc * SZ + off);
            dst[0] = make_float4(Sa[bb][0], Sa[bb][1], Sa[bb][2], Sa[bb][3]);
            dst[1] = make_float4(Sa[bb][4], Sa[bb][5], Sa[bb][6], Sa[bb][7]);
        }
    }
}

// Reduce nparts partial S slices, then squash. mode 0: OS=v; 1: OS+=v; 2: out=v.
__global__ void reduce_squash_k(const float* __restrict__ Sp, int nparts,
                                float scale, float* __restrict__ OS,
                                float* __restrict__ out, int mode)
{
    const int t = blockIdx.x * 64 + threadIdx.x;   // 0..16383
    const float4* sp = reinterpret_cast<const float4*>(Sp);
    float4 a = make_float4(0.f, 0.f, 0.f, 0.f);
    #pragma unroll 8
    for (int s = 0; s < nparts; ++s) {
        float4 v = sp[(size_t)s * (SZ / 4) + t];
        a.x += v.x; a.y += v.y; a.z += v.z; a.w += v.w;
    }
    a.x *= scale; a.y *= scale; a.z *= scale; a.w *= scale;
    float s2 = a.x * a.x + a.y * a.y + a.z * a.z + a.w * a.w;
    s2 += __shfl_xor(s2, 1, 64);
    s2 += __shfl_xor(s2, 2, 64);
    const float g = s2 / ((1.f + s2) * sqrtf(s2 + 1e-7f));
    float4 v = make_float4(g * a.x, g * a.y, g * a.z, g * a.w);
    if (mode == 0) {
        reinterpret_cast<float4*>(OS)[t] = v;
    } else if (mode == 1) {
        float4 o = reinterpret_cast<float4*>(OS)[t];
        o.x += v.x; o.y += v.y; o.z += v.z; o.w += v.w;
        reinterpret_cast<float4*>(OS)[t] = o;
    } else {
        reinterpret_cast<float4*>(out)[t] = v;
    }
}

extern "C" void kernel_launch(void* const* d_in, const int* in_sizes, int n_in,
                              void* d_out, int out_size, void* d_ws, size_t ws_size,
                              hipStream_t stream)
{
    const float* x = (const float*)d_in[0];   // [128, 2048, 8]
    const float* W = (const float*)d_in[1];   // [32, 2048, 16, 8]
    float* out = (float*)d_out;               // [128, 32, 16]

    const size_t needSp = (size_t)(NNC + 1) * SZ * sizeof(float);   // 16.9 MB
    const bool part  = ws_size >= needSp;
    const bool w16ok = ws_size >= needSp + W16_ELEMS * sizeof(ushort); // +16.8 MB
    dim3 rg(GRID), rb(512);
    dim3 sg(SZ / 4 / 64), sb(64);             // 256 blocks x 64 threads

    if (part) {
        float* Sp = (float*)d_ws;                 // [64][65536] partials
        float* OS = Sp + (size_t)NNC * SZ;        // running output sum
        ushort* W16 = (ushort*)(OS + SZ);         // fp16 W (if w16ok)

        if (w16ok) {
            const int cvtg = (int)(W16_ELEMS / 8 / 256);   // 4096 blocks
            w16cvt_k<<<dim3(cvtg), dim3(256), 0, stream>>>(W, W16);
            gemm0_v3<<<dim3(512), rb, 0, stream>>>(x, W16, Sp);
            reduce_squash_k<<<sg, sb, 0, stream>>>(Sp, NNC, 1.f / Jj, OS, out, 0);

            route_m<<<rg, rb, 0, stream>>>(x, W16, OS, Sp);
            reduce_squash_k<<<sg, sb, 0, stream>>>(Sp, NNC, 1.f, OS, out, 1);

            route_m<<<rg, rb, 0, stream>>>(x, W16, OS, Sp);
            reduce_squash_k<<<sg, sb, 0, stream>>>(Sp, NNC, 1.f, OS, out, 2);
        } else {
            gemm0_k2<0><<<dim3(512), rb, 0, stream>>>(x, W, nullptr, Sp);
            reduce_squash_k<<<sg, sb, 0, stream>>>(Sp, NNC, 1.f / Jj, OS, out, 0);

            route_k<1, 0, 0><<<rg, rb, 0, stream>>>(x, W, nullptr, OS, Sp);
            reduce_squash_k<<<sg, sb, 0, stream>>>(Sp, NNC, 1.f, OS, out, 1);

            route_k<1, 0, 0><<<rg, rb, 0, stream>>>(x, W, nullptr, OS, Sp);
            reduce_squash_k<<<sg, sb, 0, stream>>>(Sp, NNC, 1.f, OS, out, 2);
        }
    } else {
        float* S  = (float*)d_ws;
        float* OS = S + SZ;
        const size_t Sbytes = (size_t)SZ * sizeof(float);

        hipMemsetAsync(S, 0, Sbytes, stream);
        route_k<0, 1, 0><<<rg, rb, 0, stream>>>(x, W, nullptr, nullptr, S);
        reduce_squash_k<<<sg, sb, 0, stream>>>(S, 1, 1.f / Jj, OS, out, 0);

        hipMemsetAsync(S, 0, Sbytes, stream);
        route_k<1, 1, 0><<<rg, rb, 0, stream>>>(x, W, nullptr, OS, S);
        reduce_squash_k<<<sg, sb, 0, stream>>>(S, 1, 1.f, OS, out, 1);

        hipMemsetAsync(S, 0, Sbytes, stream);
        route_k<1, 1, 0><<<rg, rb, 0, stream>>>(x, W, nullptr, OS, S);
        reduce_squash_k<<<sg, sb, 0, stream>>>(S, 1, 1.f, OS, out, 2);
    }
}